// Round 5
// baseline (524.573 us; speedup 1.0000x reference)
//
#include <hip/hip_runtime.h>
#include <hip/hip_bf16.h>

typedef unsigned short u16;
typedef __bf16 bf16x8 __attribute__((ext_vector_type(8)));
typedef float floatx4 __attribute__((ext_vector_type(4)));
typedef unsigned short u16x4 __attribute__((ext_vector_type(4)));
typedef unsigned short u16x8 __attribute__((ext_vector_type(8)));

__device__ __forceinline__ float b2f(u16 v) {
  unsigned u = ((unsigned)v) << 16;
  return __builtin_bit_cast(float, u);
}
__device__ __forceinline__ u16 f2b(float f) {
  unsigned u = __builtin_bit_cast(unsigned, f);
  unsigned r = (u + 0x7FFFu + ((u >> 16) & 1u)) >> 16;
  return (u16)r;
}
__device__ __forceinline__ void cp16(const u16* g, u16* l) {
  __builtin_amdgcn_global_load_lds(
      (const __attribute__((address_space(1))) unsigned int*)g,
      (__attribute__((address_space(3))) unsigned int*)l, 16, 0, 0);
}

struct GemmArgs {
  const u16* A;
  const u16* BT0; const u16* BT1; const u16* BT2;
  const float* b0; const float* b1; const float* b2;
  const float* summ;   // nullable
  int srow0;
  u16* C0; u16* C1; u16* C2;   // bf16 outputs (ignored when Cf != null)
  float* Cf;                   // f32 output
};

// ---------------------------------------------------------------------------
// Small-M GEMM (kept for the 128-row summary branch): 128x128 tiles.
// ---------------------------------------------------------------------------
__global__ __launch_bounds__(256, 2) void gemm_bt(GemmArgs g) {
  const int z = blockIdx.z;
  const u16* A      = g.A;
  const u16* BT     = (z == 0) ? g.BT0 : (z == 1 ? g.BT1 : g.BT2);
  const float* bias = (z == 0) ? g.b0  : (z == 1 ? g.b1  : g.b2);
  u16* C            = (z == 0) ? g.C0  : (z == 1 ? g.C1  : g.C2);

  __shared__ u16 As[128 * 32];
  __shared__ u16 Bs[128 * 32];

  const int tid  = threadIdx.x;
  const int lane = tid & 63;
  const int wave = tid >> 6;
  const int quad = lane >> 4;
  const int cl   = lane & 15;
  const int wm   = wave & 1;
  const int wn   = wave >> 1;

  const size_t row0 = (size_t)blockIdx.x * 128;
  const size_t col0 = (size_t)blockIdx.y * 128;

  const int srow = lane >> 2;
  const int soff = (lane & 3) << 3;

  const u16* gA0 = A + (row0 + (size_t)(wave * 16 + srow)) * 1024 + soff;
  const u16* gA1 = gA0 + (size_t)64 * 1024;
  const u16* gB0 = BT + (col0 + (size_t)(wave * 16 + srow)) * 1024 + soff;
  const u16* gB1 = gB0 + (size_t)64 * 1024;
  u16* lA0 = As + wave * 512 + lane * 8;
  u16* lA1 = lA0 + 2048;
  u16* lB0 = Bs + wave * 512 + lane * 8;
  u16* lB1 = lB0 + 2048;

  floatx4 acc[4][4] = {};

  for (int kt = 0; kt < 1024; kt += 32) {
    __syncthreads();
    cp16(gA0, lA0); cp16(gA1, lA1);
    cp16(gB0, lB0); cp16(gB1, lB1);
    gA0 += 32; gA1 += 32; gB0 += 32; gB1 += 32;
    __syncthreads();
    bf16x8 af[4], bfr[4];
#pragma unroll
    for (int m = 0; m < 4; ++m)
      af[m] = *(const bf16x8*)&As[(wm * 64 + m * 16 + cl) * 32 + quad * 8];
#pragma unroll
    for (int n = 0; n < 4; ++n)
      bfr[n] = *(const bf16x8*)&Bs[(wn * 64 + n * 16 + cl) * 32 + quad * 8];
#pragma unroll
    for (int m = 0; m < 4; ++m)
#pragma unroll
      for (int n = 0; n < 4; ++n)
        acc[m][n] = __builtin_amdgcn_mfma_f32_16x16x32_bf16(af[m], bfr[n],
                                                            acc[m][n], 0, 0, 0);
  }

  const float* summ = g.summ;
#pragma unroll
  for (int m = 0; m < 4; ++m) {
    const size_t rbase = row0 + wm * 64 + m * 16 + quad * 4;
#pragma unroll
    for (int n = 0; n < 4; ++n) {
      const size_t c = col0 + wn * 64 + n * 16 + cl;
      const float bb = bias[c];
#pragma unroll
      for (int e = 0; e < 4; ++e) {
        float v = acc[m][n][e] + bb;
        if (summ)
          v += summ[(size_t)((int)((rbase + e) >> 8) + g.srow0) * 1024 + c];
        if (g.Cf) g.Cf[(rbase + e) * 1024 + c] = v;
        else      C[(rbase + e) * 1024 + c] = f2b(v);
      }
    }
  }
}

// ---------------------------------------------------------------------------
// 256x128-tile GEMM, software-pipelined 2-phase schedule.
//  - 8 waves as 4M x 2N; per-wave 64x64 output -> acc = 64 AGPR (frees arch
//    VGPRs for prefetch; the 256x256 variant spilled at the 128 cap).
//  - 2 phases per K-tile (m-half split, 16 MFMA each), ONE barrier per phase.
//  - All ds_reads for phase p+1 issue under phase p's MFMAs; counted
//    lgkmcnt(4/12) before MFMA (never 0); lgkmcnt(0) only at phase end.
//  - Rule #18 hardening: sched_barrier(0) right after each counted waitcnt
//    that precedes MFMAs consuming in-flight ds_read data (hipcc may hoist
//    register-only MFMA past inline-asm waitcnt despite "memory" clobber).
//  - Stage-ahead = 2 tiles into the CURRENT buffer: B(u+2)@P1(u), A(u+2)@P2(u).
//    vmcnt(2) at P1-end retires tile u+1's 6 loads before P2 prefetch-reads
//    tile u+1 (wait precedes barrier => cross-wave safe). Tail: vmcnt(0).
//  - T2 swizzle unchanged (bank conflicts measured 0).
//  LDS: buffer = A[256][64] (32KB) + B[128][64] (16KB) = 48KB, x2 = 96KB.
// ---------------------------------------------------------------------------
__global__ __launch_bounds__(512, 2) void gemm_bt256(GemmArgs g) {
  extern __shared__ char lds[];
  const int z = blockIdx.z;
  const u16* A      = g.A;
  const u16* BT     = (z == 0) ? g.BT0 : (z == 1 ? g.BT1 : g.BT2);
  const float* bias = (z == 0) ? g.b0  : (z == 1 ? g.b1  : g.b2);
  u16* C            = (z == 0) ? g.C0  : (z == 1 ? g.C1  : g.C2);

  const int tid  = threadIdx.x;
  const int lane = tid & 63;
  const int w    = tid >> 6;   // 0..7
  const int q    = lane >> 4;
  const int cl   = lane & 15;
  const int wm   = w >> 1;     // 0..3 (64-row group)
  const int wn   = w & 1;      // 0..1 (64-col group)

  const size_t row0 = (size_t)blockIdx.x * 256;
  const size_t col0 = (size_t)blockIdx.y * 128;

  // staging: per-lane inverse-swizzled global source, linear LDS dest
  const int lr  = lane >> 3;                 // row within 8-row slice
  const int lcs = ((lane & 7) ^ lr) * 8;     // swizzled 16B slot
  const u16* Ab = A  + (row0 + (size_t)(lr + w * 8)) * 1024 + lcs;
  const u16* Bb = BT + (col0 + (size_t)(lr + w * 8)) * 1024 + lcs;
  const int dOff = w * 1024 + lane * 16;     // byte offset of this lane's 16B

  // swizzled ds_read bases (bytes)
  const int swz  = (cl & 7) << 4;
  const int aBs  = (wm * 64 + cl) * 128 + ((q * 16) ^ swz);
  const int bBs  = 32768 + (wn * 64 + cl) * 128 + ((q * 16) ^ swz);

  char* const L0 = lds;
  char* const L1 = lds + 49152;

  floatx4 acc[4][4] = {};
  bf16x8 aA[2][2], aB[2][2], aT[2][2];   // m-half frags [mm][kh]
  bf16x8 bA[4][2], bB[4][2];             // B frags [nn][kh]

#define VMW2   asm volatile("s_waitcnt vmcnt(2)" ::: "memory");
#define VMW0   asm volatile("s_waitcnt vmcnt(0)" ::: "memory");
#define LGK4   asm volatile("s_waitcnt lgkmcnt(4)" ::: "memory");          \
               __builtin_amdgcn_sched_barrier(0);
#define LGK12  asm volatile("s_waitcnt lgkmcnt(12)" ::: "memory");         \
               __builtin_amdgcn_sched_barrier(0);
#define LGK0   asm volatile("s_waitcnt lgkmcnt(0)" ::: "memory");          \
               __builtin_amdgcn_sched_barrier(0);
#define BAR    __builtin_amdgcn_s_barrier();

#define STAGE_B2(T, LB)                                                       \
  _Pragma("unroll") for (int j = 0; j < 2; ++j)                               \
    cp16(Bb + (size_t)(j * 64) * 1024 + (size_t)(T) * 64,                     \
         (u16*)((LB) + 32768 + j * 8192 + dOff));

#define STAGE_A4(T, LB)                                                       \
  _Pragma("unroll") for (int j = 0; j < 4; ++j)                               \
    cp16(Ab + (size_t)(j * 64) * 1024 + (size_t)(T) * 64,                     \
         (u16*)((LB) + j * 8192 + dOff));

#define RD_AH(D, H, LB)                                                       \
  _Pragma("unroll") for (int mm = 0; mm < 2; ++mm) {                          \
    const int a0 = aBs + ((H) * 2 + mm) * 2048;                               \
    D[mm][0] = *(const bf16x8*)((LB) + a0);                                   \
    D[mm][1] = *(const bf16x8*)((LB) + (a0 ^ 64));                            \
  }

#define RD_B8(D, LB)                                                          \
  _Pragma("unroll") for (int nn = 0; nn < 4; ++nn) {                          \
    const int b0 = bBs + nn * 2048;                                           \
    D[nn][0] = *(const bf16x8*)((LB) + b0);                                   \
    D[nn][1] = *(const bf16x8*)((LB) + (b0 ^ 64));                            \
  }

#define MM16(MH, AF, BF)                                                      \
  __builtin_amdgcn_s_setprio(1);                                              \
  _Pragma("unroll") for (int mm = 0; mm < 2; ++mm)                            \
    _Pragma("unroll") for (int nn = 0; nn < 4; ++nn) {                        \
      acc[(MH) * 2 + mm][nn] = __builtin_amdgcn_mfma_f32_16x16x32_bf16(       \
          AF[mm][0], BF[nn][0], acc[(MH) * 2 + mm][nn], 0, 0, 0);             \
      acc[(MH) * 2 + mm][nn] = __builtin_amdgcn_mfma_f32_16x16x32_bf16(       \
          AF[mm][1], BF[nn][1], acc[(MH) * 2 + mm][nn], 0, 0, 0);             \
    }                                                                         \
  __builtin_amdgcn_s_setprio(0);

  // ---- prologue: stage tiles 0 (L0) and 1 (L1); load tile-0 frags ----
  STAGE_B2(0, L0) STAGE_A4(0, L0)
  STAGE_B2(1, L1) STAGE_A4(1, L1)
  VMW0           // conservative full drain once at start (prologue only)
  BAR
  RD_AH(aA, 0, L0) RD_B8(bA, L0)
  LGK0 BAR

  // ---- main: tiles 0..13 (stage 2..15), 2-tile unrolled ----
#pragma unroll 1
  for (int u0 = 0; u0 < 14; u0 += 2) {
    // tile u0 (even, buf L0; cur = aA/bA; next = aB/bB from L1)
    STAGE_B2(u0 + 2, L0)
    RD_AH(aT, 1, L0)
    LGK4  MM16(0, aA, bA)
    LGK0 VMW2 BAR
    STAGE_A4(u0 + 2, L0)
    RD_AH(aB, 0, L1) RD_B8(bB, L1)
    LGK12 MM16(1, aT, bA)
    LGK0 BAR
    // tile u0+1 (odd, buf L1; cur = aB/bB; next = aA/bA from L0)
    STAGE_B2(u0 + 3, L1)
    RD_AH(aT, 1, L1)
    LGK4  MM16(0, aB, bB)
    LGK0 VMW2 BAR
    STAGE_A4(u0 + 3, L1)
    RD_AH(aA, 0, L0) RD_B8(bA, L0)
    LGK12 MM16(1, aT, bB)
    LGK0 BAR
  }

  // ---- tile 14 (even, L0; no staging; full drain before tile-15 reads) ----
  RD_AH(aT, 1, L0)
  LGK4  MM16(0, aA, bA)
  LGK0 VMW0 BAR
  RD_AH(aB, 0, L1) RD_B8(bB, L1)
  LGK12 MM16(1, aT, bA)
  LGK0 BAR
  // ---- tile 15 (odd, L1) ----
  RD_AH(aT, 1, L1)
  LGK4  MM16(0, aB, bB)
  LGK0  MM16(1, aT, bB)

#undef MM16
#undef RD_B8
#undef RD_AH
#undef STAGE_A4
#undef STAGE_B2
#undef BAR
#undef LGK0
#undef LGK12
#undef LGK4
#undef VMW0
#undef VMW2

  const float* summ = g.summ;
#pragma unroll
  for (int m = 0; m < 4; ++m) {
    const size_t rbase = row0 + wm * 64 + m * 16 + q * 4;
#pragma unroll
    for (int n = 0; n < 4; ++n) {
      const size_t c = col0 + wn * 64 + n * 16 + cl;
      const float bb = bias[c];
#pragma unroll
      for (int e = 0; e < 4; ++e) {
        float v = acc[m][n][e] + bb;
        if (summ)
          v += summ[(size_t)((int)((rbase + e) >> 8) + g.srow0) * 1024 + c];
        if (g.Cf) g.Cf[(rbase + e) * 1024 + c] = v;
        else      C[(rbase + e) * 1024 + c] = f2b(v);
      }
    }
  }
}

// ---------------------------------------------------------------------------
// Local block attention. grid (4 qtiles, 16 heads, nblk), 256 threads.
// ---------------------------------------------------------------------------
__global__ __launch_bounds__(256, 2) void local_attn(
    const u16* __restrict__ Q, const u16* __restrict__ Kt,
    const u16* __restrict__ Vt, const float* __restrict__ pbias,
    u16* __restrict__ ctx) {
  const int qt  = blockIdx.x;
  const int h   = blockIdx.y;
  const int blk = blockIdx.z;
  const int tid  = threadIdx.x;
  const int lane = tid & 63;
  const int w    = tid >> 6;
  const int quad = lane >> 4;
  const int cl   = lane & 15;

  __shared__ u16 BufA[64 * 72];
  __shared__ u16 BufB[64 * 72];

  const size_t tok0  = (size_t)blk * 256;
  const size_t qrow0 = tok0 + qt * 64;
  const int hc = h * 64;

  for (int i = tid; i < 512; i += 256) {
    const int row = i >> 3, c8 = (i & 7) * 8;
    *(u16x8*)&BufA[row * 72 + c8] =
        *(const u16x8*)&Q[(qrow0 + row) * 1024 + hc + c8];
  }

  floatx4 accS[16] = {};
#pragma unroll
  for (int kc = 0; kc < 4; ++kc) {
    __syncthreads();
    for (int i = tid; i < 512; i += 256) {
      const int row = i >> 3, c8 = (i & 7) * 8;
      *(u16x8*)&BufB[row * 72 + c8] =
          *(const u16x8*)&Kt[(tok0 + kc * 64 + row) * 1024 + hc + c8];
    }
    __syncthreads();
#pragma unroll
    for (int ki = 0; ki < 2; ++ki) {
      const bf16x8 aq =
          *(const bf16x8*)&BufA[(w * 16 + cl) * 72 + ki * 32 + quad * 8];
#pragma unroll
      for (int n = 0; n < 4; ++n) {
        const bf16x8 bk =
            *(const bf16x8*)&BufB[(n * 16 + cl) * 72 + ki * 32 + quad * 8];
        accS[kc * 4 + n] = __builtin_amdgcn_mfma_f32_16x16x32_bf16(
            aq, bk, accS[kc * 4 + n], 0, 0, 0);
      }
    }
  }

  float mrow[4] = {-1e30f, -1e30f, -1e30f, -1e30f};
#pragma unroll
  for (int r = 0; r < 4; ++r) {
    const float* brow = pbias + ((size_t)h << 16) +
                        (size_t)(qt * 64 + w * 16 + quad * 4 + r) * 256 + cl;
#pragma unroll
    for (int n = 0; n < 16; ++n) {
      float s = accS[n][r] * 0.125f + brow[n * 16];
      accS[n][r] = s;
      mrow[r] = fmaxf(mrow[r], s);
    }
  }
#pragma unroll
  for (int r = 0; r < 4; ++r) {
#pragma unroll
    for (int st = 1; st < 16; st <<= 1)
      mrow[r] = fmaxf(mrow[r], __shfl_xor(mrow[r], st));
  }
  float lsum[4] = {0.f, 0.f, 0.f, 0.f};
#pragma unroll
  for (int n = 0; n < 16; ++n) {
#pragma unroll
    for (int r = 0; r < 4; ++r) {
      float p = exp2f((accS[n][r] - mrow[r]) * 1.44269504f);
      accS[n][r] = p;
      lsum[r] += p;
    }
  }
#pragma unroll
  for (int r = 0; r < 4; ++r) {
#pragma unroll
    for (int st = 1; st < 16; st <<= 1)
      lsum[r] += __shfl_xor(lsum[r], st);
  }

  floatx4 accO[4] = {};
#pragma unroll
  for (int kc = 0; kc < 4; ++kc) {
    __syncthreads();
#pragma unroll
    for (int nn = 0; nn < 4; ++nn)
#pragma unroll
      for (int r = 0; r < 4; ++r)
        BufA[(w * 16 + quad * 4 + r) * 72 + nn * 16 + cl] =
            f2b(accS[kc * 4 + nn][r]);
    for (int i = tid; i < 512; i += 256) {
      const int key = i & 63, dh0 = (i >> 6) * 8;
      u16x8 v = *(const u16x8*)&Vt[(tok0 + kc * 64 + key) * 1024 + hc + dh0];
#pragma unroll
      for (int j = 0; j < 8; ++j) BufB[(dh0 + j) * 72 + key] = v[j];
    }
    __syncthreads();
#pragma unroll
    for (int ki = 0; ki < 2; ++ki) {
      const bf16x8 ap =
          *(const bf16x8*)&BufA[(w * 16 + cl) * 72 + ki * 32 + quad * 8];
#pragma unroll
      for (int nd = 0; nd < 4; ++nd) {
        const bf16x8 bv =
            *(const bf16x8*)&BufB[(nd * 16 + cl) * 72 + ki * 32 + quad * 8];
        accO[nd] = __builtin_amdgcn_mfma_f32_16x16x32_bf16(ap, bv, accO[nd],
                                                           0, 0, 0);
      }
    }
  }

  float inv[4];
#pragma unroll
  for (int r = 0; r < 4; ++r) inv[r] = 1.0f / lsum[r];
#pragma unroll
  for (int nd = 0; nd < 4; ++nd)
#pragma unroll
    for (int r = 0; r < 4; ++r)
      ctx[(qrow0 + w * 16 + quad * 4 + r) * 1024 + hc + nd * 16 + cl] =
          f2b(accO[nd][r] * inv[r]);
}

// ---------------------------------------------------------------------------
// Conversions & summary-branch helpers
// ---------------------------------------------------------------------------
__global__ void cvt_x(const float* __restrict__ x, u16* __restrict__ xb) {
  const size_t i = ((size_t)blockIdx.x * 256 + threadIdx.x) * 4;
  float4 v = *(const float4*)&x[i];
  u16x4 o;
  o[0] = f2b(v.x); o[1] = f2b(v.y); o[2] = f2b(v.z); o[3] = f2b(v.w);
  *(u16x4*)&xb[i] = o;
}

__global__ void block_mean(const float* __restrict__ x, u16* __restrict__ xm) {
  const int g = blockIdx.x >> 2;
  const int d = ((blockIdx.x & 3) << 8) + threadIdx.x;
  const float* p = x + (size_t)g * 256 * 1024 + d;
  float s = 0.f;
  for (int t = 0; t < 256; ++t) s += p[(size_t)t * 1024];
  xm[(size_t)g * 1024 + d] = f2b(s * (1.0f / 256.0f));
}

__global__ void summ_attn(const u16* __restrict__ SQ, const u16* __restrict__ SK,
                          const u16* __restrict__ SV, u16* __restrict__ sctx) {
  const int b = blockIdx.x >> 4;
  const int h = blockIdx.x & 15;
  const int t = threadIdx.x;
  __shared__ float Qf[16][64];
  __shared__ float Kf[16][64];
  __shared__ float Vf[16][64];
  __shared__ float sc[16][16];
  for (int i = t; i < 1024; i += 64) {
    const int r = i >> 6, d = i & 63;
    const size_t off = (size_t)(b * 16 + r) * 1024 + h * 64 + d;
    Qf[r][d] = b2f(SQ[off]);
    Kf[r][d] = b2f(SK[off]);
    Vf[r][d] = b2f(SV[off]);
  }
  __syncthreads();
  {
    const int i = t >> 2, j0 = t & 3;
#pragma unroll
    for (int jj = 0; jj < 4; ++jj) {
      const int j = j0 + jj * 4;
      float s = 0.f;
      for (int d = 0; d < 64; ++d) s += Qf[i][d] * Kf[j][d];
      sc[i][j] = s * 0.125f;
    }
  }
  __syncthreads();
  if (t < 16) {
    float m = -1e30f;
    for (int j = 0; j < 16; ++j) m = fmaxf(m, sc[t][j]);
    float l = 0.f;
    for (int j = 0; j < 16; ++j) {
      float p = exp2f((sc[t][j] - m) * 1.44269504f);
      sc[t][j] = p;
      l += p;
    }
    const float inv = 1.0f / l;
    for (int j = 0; j < 16; ++j) sc[t][j] *= inv;
  }
  __syncthreads();
  {
    const int i = t >> 2, d0 = (t & 3) * 16;
    for (int dd = 0; dd < 16; ++dd) {
      float a = 0.f;
      for (int j = 0; j < 16; ++j) a += sc[i][j] * Vf[j][d0 + dd];
      sctx[(size_t)(b * 16 + i) * 1024 + h * 64 + d0 + dd] = f2b(a);
    }
  }
}

struct TPtrs { const float* src[9]; u16* dst[9]; };

__global__ void cvt_transpose9(TPtrs p) {
  const float* src = p.src[blockIdx.z];
  u16* dst         = p.dst[blockIdx.z];
  __shared__ u16 tile[64][72];
  const int r0 = blockIdx.x * 64, c0 = blockIdx.y * 64;
  for (int i = threadIdx.x; i < 1024; i += 256) {
    const int row = i >> 4, c4 = (i & 15) * 4;
    float4 v = *(const float4*)&src[(size_t)(r0 + row) * 1024 + c0 + c4];
    tile[row][c4 + 0] = f2b(v.x);
    tile[row][c4 + 1] = f2b(v.y);
    tile[row][c4 + 2] = f2b(v.z);
    tile[row][c4 + 3] = f2b(v.w);
  }
  __syncthreads();
  for (int i = threadIdx.x; i < 512; i += 256) {
    const int row = i >> 3, c8 = (i & 7) * 8;
    u16x8 v;
#pragma unroll
    for (int j = 0; j < 8; ++j) v[j] = tile[c8 + j][row];
    *(u16x8*)&dst[(size_t)(c0 + row) * 1024 + r0 + c8] = v;
  }
}

// ---------------------------------------------------------------------------
extern "C" void kernel_launch(void* const* d_in, const int* in_sizes, int n_in,
                              void* d_out, int out_size, void* d_ws, size_t ws_size,
                              hipStream_t stream) {
  const float* x    = (const float*)d_in[0];
  const float* lqw  = (const float*)d_in[1];
  const float* lqb  = (const float*)d_in[2];
  const float* lkw  = (const float*)d_in[3];
  const float* lkb  = (const float*)d_in[4];
  const float* lvw  = (const float*)d_in[5];
  const float* lvb  = (const float*)d_in[6];
  const float* low_ = (const float*)d_in[7];
  const float* lob  = (const float*)d_in[8];
  const float* pb   = (const float*)d_in[9];
  const float* sqw  = (const float*)d_in[10];
  const float* sqb  = (const float*)d_in[11];
  const float* skw  = (const float*)d_in[12];
  const float* skb  = (const float*)d_in[13];
  const float* svw  = (const float*)d_in[14];
  const float* svb  = (const float*)d_in[15];
  const float* sow  = (const float*)d_in[16];
  const float* sob  = (const float*)d_in[17];
  const float* smw  = (const float*)d_in[18];
  const float* smb  = (const float*)d_in[19];

  static int s_attr_done = 0;
  if (!s_attr_done) {
    (void)hipFuncSetAttribute((const void*)gemm_bt256,
                              hipFuncAttributeMaxDynamicSharedMemorySize,
                              98304);
    s_attr_done = 1;
  }

  char* W = (char*)d_ws;
  size_t off = 0;
  u16* wt[9];
  for (int i = 0; i < 9; ++i) { wt[i] = (u16*)(W + off); off += (size_t)1024 * 1024 * 2; }
  u16* Xb  = (u16*)(W + off); off += (size_t)16384 * 1024 * 2;
  u16* XM  = (u16*)(W + off); off += (size_t)128 * 1024 * 2;
  u16* SMR = (u16*)(W + off); off += (size_t)128 * 1024 * 2;
  u16* SQp = (u16*)(W + off); off += (size_t)128 * 1024 * 2;
  u16* SKp = (u16*)(W + off); off += (size_t)128 * 1024 * 2;
  u16* SVp = (u16*)(W + off); off += (size_t)128 * 1024 * 2;
  u16* SCT = (u16*)(W + off); off += (size_t)128 * 1024 * 2;
  float* SMM = (float*)(W + off); off += (size_t)128 * 1024 * 4;
  const size_t fixedB = off;

  int CH = 256;
  for (int c = 16384; c >= 256; c >>= 1) {
    if (fixedB + (size_t)4 * c * 1024 * 2 <= ws_size) { CH = c; break; }
  }
  u16* Qb  = (u16*)(W + fixedB);
  u16* Kb  = Qb + (size_t)CH * 1024;
  u16* Vb  = Kb + (size_t)CH * 1024;
  u16* CTX = Vb + (size_t)CH * 1024;

  TPtrs tp;
  tp.src[0] = lqw; tp.src[1] = lkw; tp.src[2] = lvw; tp.src[3] = low_;
  tp.src[4] = sqw; tp.src[5] = skw; tp.src[6] = svw; tp.src[7] = sow;
  tp.src[8] = smw;
  for (int i = 0; i < 9; ++i) tp.dst[i] = wt[i];
  cvt_transpose9<<<dim3(16, 16, 9), 256, 0, stream>>>(tp);

  cvt_x<<<dim3(16384), 256, 0, stream>>>(x, Xb);
  block_mean<<<dim3(256), 256, 0, stream>>>(x, XM);

  GemmArgs g1{};
  g1.A = XM; g1.BT0 = g1.BT1 = g1.BT2 = wt[8];
  g1.b0 = g1.b1 = g1.b2 = smb; g1.summ = nullptr; g1.srow0 = 0;
  g1.C0 = g1.C1 = g1.C2 = SMR; g1.Cf = nullptr;
  gemm_bt<<<dim3(1, 8, 1), 256, 0, stream>>>(g1);

  GemmArgs g2{};
  g2.A = SMR; g2.BT0 = wt[4]; g2.BT1 = wt[5]; g2.BT2 = wt[6];
  g2.b0 = sqb; g2.b1 = skb; g2.b2 = svb; g2.summ = nullptr; g2.srow0 = 0;
  g2.C0 = SQp; g2.C1 = SKp; g2.C2 = SVp; g2.Cf = nullptr;
  gemm_bt<<<dim3(1, 8, 3), 256, 0, stream>>>(g2);

  summ_attn<<<dim3(64), 64, 0, stream>>>(SQp, SKp, SVp, SCT);

  GemmArgs g3{};
  g3.A = SCT; g3.BT0 = g3.BT1 = g3.BT2 = wt[7];
  g3.b0 = g3.b1 = g3.b2 = sob; g3.summ = nullptr; g3.srow0 = 0;
  g3.C0 = g3.C1 = g3.C2 = nullptr; g3.Cf = SMM;
  gemm_bt<<<dim3(1, 8, 1), 256, 0, stream>>>(g3);

  for (int base = 0; base < 16384; base += CH) {
    GemmArgs g4{};
    g4.A = Xb + (size_t)base * 1024;
    g4.BT0 = wt[0]; g4.BT1 = wt[1]; g4.BT2 = wt[2];
    g4.b0 = lqb; g4.b1 = lkb; g4.b2 = lvb; g4.summ = nullptr; g4.srow0 = 0;
    g4.C0 = Qb; g4.C1 = Kb; g4.C2 = Vb; g4.Cf = nullptr;
    gemm_bt256<<<dim3(CH / 256, 8, 3), 512, 98304, stream>>>(g4);

    local_attn<<<dim3(4, 16, CH / 256), 256, 0, stream>>>(Qb, Kb, Vb, pb, CTX);

    GemmArgs g5{};
    g5.A = CTX; g5.BT0 = g5.BT1 = g5.BT2 = wt[3];
    g5.b0 = g5.b1 = g5.b2 = lob; g5.summ = SMM; g5.srow0 = base >> 8;
    g5.C0 = g5.C1 = g5.C2 = nullptr;
    g5.Cf = (float*)d_out + (size_t)base * 1024;
    gemm_bt256<<<dim3(CH / 256, 8, 1), 512, 98304, stream>>>(g5);
  }

  (void)in_sizes; (void)n_in; (void)out_size;
}

// Round 6
// 504.972 us; speedup vs baseline: 1.0388x; 1.0388x over previous
//
#include <hip/hip_runtime.h>
#include <hip/hip_bf16.h>

typedef unsigned short u16;
typedef __bf16 bf16x8 __attribute__((ext_vector_type(8)));
typedef float floatx4 __attribute__((ext_vector_type(4)));
typedef unsigned short u16x4 __attribute__((ext_vector_type(4)));
typedef unsigned short u16x8 __attribute__((ext_vector_type(8)));

__device__ __forceinline__ float b2f(u16 v) {
  unsigned u = ((unsigned)v) << 16;
  return __builtin_bit_cast(float, u);
}
__device__ __forceinline__ u16 f2b(float f) {
  unsigned u = __builtin_bit_cast(unsigned, f);
  unsigned r = (u + 0x7FFFu + ((u >> 16) & 1u)) >> 16;
  return (u16)r;
}
__device__ __forceinline__ void cp16(const u16* g, u16* l) {
  __builtin_amdgcn_global_load_lds(
      (const __attribute__((address_space(1))) unsigned int*)g,
      (__attribute__((address_space(3))) unsigned int*)l, 16, 0, 0);
}

struct GemmArgs {
  const u16* A;
  const u16* BT0; const u16* BT1; const u16* BT2;
  const float* b0; const float* b1; const float* b2;
  const float* summ;   // nullable
  int srow0;
  u16* C0; u16* C1; u16* C2;   // bf16 outputs (ignored when Cf != null)
  float* Cf;                   // f32 output
};

// ---------------------------------------------------------------------------
// Small-M GEMM (kept for the 128-row summary branch): 128x128 tiles.
// ---------------------------------------------------------------------------
__global__ __launch_bounds__(256, 2) void gemm_bt(GemmArgs g) {
  const int z = blockIdx.z;
  const u16* A      = g.A;
  const u16* BT     = (z == 0) ? g.BT0 : (z == 1 ? g.BT1 : g.BT2);
  const float* bias = (z == 0) ? g.b0  : (z == 1 ? g.b1  : g.b2);
  u16* C            = (z == 0) ? g.C0  : (z == 1 ? g.C1  : g.C2);

  __shared__ u16 As[128 * 32];
  __shared__ u16 Bs[128 * 32];

  const int tid  = threadIdx.x;
  const int lane = tid & 63;
  const int wave = tid >> 6;
  const int quad = lane >> 4;
  const int cl   = lane & 15;
  const int wm   = wave & 1;
  const int wn   = wave >> 1;

  const size_t row0 = (size_t)blockIdx.x * 128;
  const size_t col0 = (size_t)blockIdx.y * 128;

  const int srow = lane >> 2;
  const int soff = (lane & 3) << 3;

  const u16* gA0 = A + (row0 + (size_t)(wave * 16 + srow)) * 1024 + soff;
  const u16* gA1 = gA0 + (size_t)64 * 1024;
  const u16* gB0 = BT + (col0 + (size_t)(wave * 16 + srow)) * 1024 + soff;
  const u16* gB1 = gB0 + (size_t)64 * 1024;
  u16* lA0 = As + wave * 512 + lane * 8;
  u16* lA1 = lA0 + 2048;
  u16* lB0 = Bs + wave * 512 + lane * 8;
  u16* lB1 = lB0 + 2048;

  floatx4 acc[4][4] = {};

  for (int kt = 0; kt < 1024; kt += 32) {
    __syncthreads();
    cp16(gA0, lA0); cp16(gA1, lA1);
    cp16(gB0, lB0); cp16(gB1, lB1);
    gA0 += 32; gA1 += 32; gB0 += 32; gB1 += 32;
    __syncthreads();
    bf16x8 af[4], bfr[4];
#pragma unroll
    for (int m = 0; m < 4; ++m)
      af[m] = *(const bf16x8*)&As[(wm * 64 + m * 16 + cl) * 32 + quad * 8];
#pragma unroll
    for (int n = 0; n < 4; ++n)
      bfr[n] = *(const bf16x8*)&Bs[(wn * 64 + n * 16 + cl) * 32 + quad * 8];
#pragma unroll
    for (int m = 0; m < 4; ++m)
#pragma unroll
      for (int n = 0; n < 4; ++n)
        acc[m][n] = __builtin_amdgcn_mfma_f32_16x16x32_bf16(af[m], bfr[n],
                                                            acc[m][n], 0, 0, 0);
  }

  const float* summ = g.summ;
#pragma unroll
  for (int m = 0; m < 4; ++m) {
    const size_t rbase = row0 + wm * 64 + m * 16 + quad * 4;
#pragma unroll
    for (int n = 0; n < 4; ++n) {
      const size_t c = col0 + wn * 64 + n * 16 + cl;
      const float bb = bias[c];
#pragma unroll
      for (int e = 0; e < 4; ++e) {
        float v = acc[m][n][e] + bb;
        if (summ)
          v += summ[(size_t)((int)((rbase + e) >> 8) + g.srow0) * 1024 + c];
        if (g.Cf) g.Cf[(rbase + e) * 1024 + c] = v;
        else      C[(rbase + e) * 1024 + c] = f2b(v);
      }
    }
  }
}

// ---------------------------------------------------------------------------
// 256x256-tile GEMM, m201-style 4-phase schedule, minimal register footprint.
// (EXACT round-3 version: best verified, g4 = 132 us, 510.6 us total.)
// ---------------------------------------------------------------------------
__global__ __launch_bounds__(512, 2) void gemm_bt256(GemmArgs g) {
  extern __shared__ char lds[];
  const int z = blockIdx.z;
  const u16* A      = g.A;
  const u16* BT     = (z == 0) ? g.BT0 : (z == 1 ? g.BT1 : g.BT2);
  const float* bias = (z == 0) ? g.b0  : (z == 1 ? g.b1  : g.b2);
  u16* C            = (z == 0) ? g.C0  : (z == 1 ? g.C1  : g.C2);

  const int tid  = threadIdx.x;
  const int lane = tid & 63;
  const int w    = tid >> 6;   // 0..7
  const int q    = lane >> 4;
  const int cl   = lane & 15;
  const int wm   = w >> 2;     // 0..1
  const int wn   = w & 3;      // 0..3

  const size_t row0 = (size_t)blockIdx.x * 256;
  const size_t col0 = (size_t)blockIdx.y * 256;

  // staging source (per-lane inverse-swizzled global address)
  const int lr  = lane >> 3;
  const int lcs = ((lane & 7) ^ lr) * 8;
  const u16* Ab = A  + (row0 + (size_t)lr) * 1024 + lcs;
  const u16* Bb = BT + (col0 + (size_t)lr) * 1024 + lcs;
  const int wa8 = w * 8;
  const int wbr = (w >> 2) * 64 + (w & 3) * 8;

  // swizzled ds_read bases
  const int swz = (cl & 7) << 4;
  const int aB0 = (wm * 128 + cl) * 128 + ((q * 16) ^ swz);
  const int aB1 = aB0 ^ 64;
  const int bB0 = 32768 + (wn * 64 + cl) * 128 + ((q * 16) ^ swz);
  const int bB1 = bB0 ^ 64;

  char* const L0 = lds;
  char* const L1 = lds + 65536;

  floatx4 acc[8][4] = {};
  bf16x8 aF0[4], aF1[4];            // current A quadrant (k-half 0 / 1)
  bf16x8 b0h0[2], b0h1[2];          // B half s0
  bf16x8 b1h0[2], b1h1[2];          // B half s1

#define VMW(N) asm volatile("s_waitcnt vmcnt(" #N ")" ::: "memory");
#define LGK0   asm volatile("s_waitcnt lgkmcnt(0)" ::: "memory");
#define BAR    __builtin_amdgcn_s_barrier();

#define STAGE_A(QA, T, LBASE)                                                 \
  { const int r0s = (QA) * 64 + wa8;                                          \
    cp16(Ab + (size_t)r0s * 1024 + (size_t)(T) * 64,                          \
         (u16*)((LBASE) + r0s * 128));                                        \
    const int r1s = r0s + 128;                                                \
    cp16(Ab + (size_t)r1s * 1024 + (size_t)(T) * 64,                          \
         (u16*)((LBASE) + r1s * 128)); }

#define STAGE_B(QB, T, LBASE)                                                 \
  { const int r0s = wbr + (QB) * 32;                                          \
    cp16(Bb + (size_t)r0s * 1024 + (size_t)(T) * 64,                          \
         (u16*)((LBASE) + 32768 + r0s * 128));                                \
    const int r1s = r0s + 128;                                                \
    cp16(Bb + (size_t)r1s * 1024 + (size_t)(T) * 64,                          \
         (u16*)((LBASE) + 32768 + r1s * 128)); }

#define RD_AQ(QM, LB)                                                         \
  _Pragma("unroll") for (int mm = 0; mm < 4; ++mm) {                          \
    const int ro = (QM) * 8192 + mm * 2048;                                   \
    aF0[mm] = *(const bf16x8*)((LB) + aB0 + ro);                              \
    aF1[mm] = *(const bf16x8*)((LB) + aB1 + ro);                              \
  }

#define RD_BH(D0, D1, QN, LB)                                                 \
  _Pragma("unroll") for (int nn = 0; nn < 2; ++nn) {                          \
    const int co = (QN) * 4096 + nn * 2048;                                   \
    D0[nn] = *(const bf16x8*)((LB) + bB0 + co);                               \
    D1[nn] = *(const bf16x8*)((LB) + bB1 + co);                               \
  }

#define MMH(QM, QN, B0, B1)                                                   \
  __builtin_amdgcn_s_setprio(1);                                              \
  _Pragma("unroll") for (int mm = 0; mm < 4; ++mm)                            \
    _Pragma("unroll") for (int nn = 0; nn < 2; ++nn)                          \
      acc[(QM) * 4 + mm][(QN) * 2 + nn] =                                     \
          __builtin_amdgcn_mfma_f32_16x16x32_bf16(                            \
              aF0[mm], B0[nn], acc[(QM) * 4 + mm][(QN) * 2 + nn], 0, 0, 0);   \
  _Pragma("unroll") for (int mm = 0; mm < 4; ++mm)                            \
    _Pragma("unroll") for (int nn = 0; nn < 2; ++nn)                          \
      acc[(QM) * 4 + mm][(QN) * 2 + nn] =                                     \
          __builtin_amdgcn_mfma_f32_16x16x32_bf16(                            \
              aF1[mm], B1[nn], acc[(QM) * 4 + mm][(QN) * 2 + nn], 0, 0, 0);   \
  __builtin_amdgcn_s_setprio(0);

  // tile u (buffer LB) staging tile T=u+2 into LB; WAITSTMT at P4-end.
#define TILE(LB, T, WAITSTMT)                                                 \
  RD_AQ(0, LB) RD_BH(b0h0, b0h1, 0, LB)                                       \
  BAR LGK0 MMH(0, 0, b0h0, b0h1) BAR                                          \
  RD_BH(b1h0, b1h1, 1, LB)                                                    \
  STAGE_A(0, T, LB) STAGE_B(0, T, LB)                                         \
  BAR LGK0 MMH(0, 1, b1h0, b1h1) BAR                                          \
  RD_AQ(1, LB)                                                                \
  STAGE_B(1, T, LB)                                                           \
  BAR LGK0 MMH(1, 1, b1h0, b1h1) BAR                                          \
  STAGE_A(1, T, LB)                                                           \
  BAR MMH(1, 0, b0h0, b0h1) WAITSTMT BAR

  // ---- prologue: stage tiles 0 and 1 ----
  STAGE_A(0, 0, L0) STAGE_B(0, 0, L0) STAGE_B(1, 0, L0) STAGE_A(1, 0, L0)
  STAGE_A(0, 1, L1) STAGE_B(0, 1, L1) STAGE_B(1, 1, L1) STAGE_A(1, 1, L1)
  VMW(8)   // newest 8 = tile 1's loads -> tile 0 fully retired (this wave)
  BAR      // -> all waves

  // ---- main: tiles 0..13 stage tiles 2..15 ----
#pragma unroll 1
  for (int u0 = 0; u0 < 14; u0 += 2) {
    TILE(L0, u0 + 2, VMW(8))
    TILE(L1, u0 + 3, VMW(8))
  }

  // ---- tile 14 (L0, no staging; drain tile-15 loads at end) ----
  RD_AQ(0, L0) RD_BH(b0h0, b0h1, 0, L0)
  BAR LGK0 MMH(0, 0, b0h0, b0h1) BAR
  RD_BH(b1h0, b1h1, 1, L0)
  BAR LGK0 MMH(0, 1, b1h0, b1h1) BAR
  RD_AQ(1, L0)
  BAR LGK0 MMH(1, 1, b1h0, b1h1) BAR
  BAR MMH(1, 0, b0h0, b0h1) VMW(0) BAR
  // ---- tile 15 (L1) ----
  RD_AQ(0, L1) RD_BH(b0h0, b0h1, 0, L1)
  BAR LGK0 MMH(0, 0, b0h0, b0h1) BAR
  RD_BH(b1h0, b1h1, 1, L1)
  BAR LGK0 MMH(0, 1, b1h0, b1h1) BAR
  RD_AQ(1, L1)
  BAR LGK0 MMH(1, 1, b1h0, b1h1)
  MMH(1, 0, b0h0, b0h1)

#undef TILE
#undef MMH
#undef RD_BH
#undef RD_AQ
#undef STAGE_B
#undef STAGE_A
#undef BAR
#undef LGK0
#undef VMW

  const float* summ = g.summ;
#pragma unroll
  for (int m = 0; m < 8; ++m) {
    const size_t rbase = row0 + wm * 128 + m * 16 + q * 4;
#pragma unroll
    for (int n = 0; n < 4; ++n) {
      const size_t c = col0 + wn * 64 + n * 16 + cl;
      const float bb = bias[c];
#pragma unroll
      for (int e = 0; e < 4; ++e) {
        float v = acc[m][n][e] + bb;
        if (summ)
          v += summ[(size_t)((int)((rbase + e) >> 8) + g.srow0) * 1024 + c];
        if (g.Cf) g.Cf[(rbase + e) * 1024 + c] = v;
        else      C[(rbase + e) * 1024 + c] = f2b(v);
      }
    }
  }
}

// ---------------------------------------------------------------------------
// Local block attention v2. grid (4 qtiles, 16 heads, nblk), 256 threads.
//  - K tile (256x64, 32KB) staged ONCE via async global_load_lds with the
//    verified T2 inverse-swizzle (same math as gemm_bt256; 0 bank conflicts).
//  - Q fragments loaded directly from global (2 loads/lane) - no Q LDS.
//  - QK^T: ONE barrier then 32 back-to-back MFMAs (was 8 barriers + 8 stages).
//  - PV: P chunk is own-wave rows (no barrier needed for P); 2 barriers per
//    V chunk (WAR + visibility). Total barriers 16 -> 8.
//  - LDS 50176 B -> 3 blocks/CU.
// ---------------------------------------------------------------------------
__global__ __launch_bounds__(256, 3) void local_attn(
    const u16* __restrict__ Q, const u16* __restrict__ Kt,
    const u16* __restrict__ Vt, const float* __restrict__ pbias,
    u16* __restrict__ ctx) {
  const int qt  = blockIdx.x;
  const int h   = blockIdx.y;
  const int blk = blockIdx.z;
  const int tid  = threadIdx.x;
  const int lane = tid & 63;
  const int w    = tid >> 6;
  const int quad = lane >> 4;
  const int cl   = lane & 15;

  __shared__ u16 Ks[256 * 64];   // swizzled K tile (32 KB)
  __shared__ u16 Ps[64 * 72];    // P chunk, pad-72 (9 KB)
  __shared__ u16 Vs[64 * 72];    // V^T chunk, pad-72 (9 KB)

  const size_t tok0  = (size_t)blk * 256;
  const size_t qrow0 = tok0 + qt * 64;
  const int hc = h * 64;

  // ---- stage K (8 rounds of cp16; inverse-swizzled source, linear dest) ----
  const int lr  = lane >> 3;
  const int lcs = ((lane & 7) ^ lr) * 8;
  {
    const u16* Kb = Kt + (tok0 + (size_t)(w * 8 + lr)) * 1024 + hc + lcs;
    u16* ld = Ks + w * 512 + lane * 8;   // w*1024B + lane*16B (u16 units)
#pragma unroll
    for (int rnd = 0; rnd < 8; ++rnd)
      cp16(Kb + (size_t)(rnd * 32) * 1024, ld + rnd * 2048);
  }
  // ---- Q fragments direct from global ----
  const u16* qrow = Q + (qrow0 + (size_t)(w * 16 + cl)) * 1024 + hc + quad * 8;
  const bf16x8 aq0 = *(const bf16x8*)(qrow);
  const bf16x8 aq1 = *(const bf16x8*)(qrow + 32);

  asm volatile("s_waitcnt vmcnt(0)" ::: "memory");
  __syncthreads();

  // ---- QK^T: 32 MFMAs, swizzled ds_read_b128 from Ks ----
  const int swz = (cl & 7) << 4;
  floatx4 accS[16];
#pragma unroll
  for (int n = 0; n < 16; ++n) {
    const int kb = (n * 16 + cl) * 128 + ((quad * 16) ^ swz);
    const bf16x8 bk0 = *(const bf16x8*)((const char*)Ks + kb);
    const bf16x8 bk1 = *(const bf16x8*)((const char*)Ks + (kb ^ 64));
    floatx4 a = {};
    a = __builtin_amdgcn_mfma_f32_16x16x32_bf16(aq0, bk0, a, 0, 0, 0);
    a = __builtin_amdgcn_mfma_f32_16x16x32_bf16(aq1, bk1, a, 0, 0, 0);
    accS[n] = a;
  }

  // ---- softmax over 256 keys (unchanged math) ----
  float mrow[4] = {-1e30f, -1e30f, -1e30f, -1e30f};
#pragma unroll
  for (int r = 0; r < 4; ++r) {
    const float* brow = pbias + ((size_t)h << 16) +
                        (size_t)(qt * 64 + w * 16 + quad * 4 + r) * 256 + cl;
#pragma unroll
    for (int n = 0; n < 16; ++n) {
      float s = accS[n][r] * 0.125f + brow[n * 16];
      accS[n][r] = s;
      mrow[r] = fmaxf(mrow[r], s);
    }
  }
#pragma unroll
  for (int r = 0; r < 4; ++r) {
#pragma unroll
    for (int st = 1; st < 16; st <<= 1)
      mrow[r] = fmaxf(mrow[r], __shfl_xor(mrow[r], st));
  }
  float lsum[4] = {0.f, 0.f, 0.f, 0.f};
#pragma unroll
  for (int n = 0; n < 16; ++n) {
#pragma unroll
    for (int r = 0; r < 4; ++r) {
      float p = exp2f((accS[n][r] - mrow[r]) * 1.44269504f);
      accS[n][r] = p;
      lsum[r] += p;
    }
  }
#pragma unroll
  for (int r = 0; r < 4; ++r) {
#pragma unroll
    for (int st = 1; st < 16; st <<= 1)
      lsum[r] += __shfl_xor(lsum[r], st);
  }

  // ---- O = P @ V, chunked over 4 key-chunks of 64 ----
  floatx4 accO[4] = {};
#pragma unroll
  for (int kc = 0; kc < 4; ++kc) {
    if (kc) __syncthreads();   // WAR: Vs/Ps reuse
#pragma unroll
    for (int nn = 0; nn < 4; ++nn)
#pragma unroll
      for (int r = 0; r < 4; ++r)
        Ps[(w * 16 + quad * 4 + r) * 72 + nn * 16 + cl] =
            f2b(accS[kc * 4 + nn][r]);
    for (int i = tid; i < 512; i += 256) {
      const int key = i & 63, dh0 = (i >> 6) * 8;
      u16x8 v = *(const u16x8*)&Vt[(tok0 + kc * 64 + key) * 1024 + hc + dh0];
#pragma unroll
      for (int j = 0; j < 8; ++j) Vs[(dh0 + j) * 72 + key] = v[j];
    }
    __syncthreads();
#pragma unroll
    for (int ki = 0; ki < 2; ++ki) {
      const bf16x8 ap =
          *(const bf16x8*)&Ps[(w * 16 + cl) * 72 + ki * 32 + quad * 8];
#pragma unroll
      for (int nd = 0; nd < 4; ++nd) {
        const bf16x8 bv =
            *(const bf16x8*)&Vs[(nd * 16 + cl) * 72 + ki * 32 + quad * 8];
        accO[nd] = __builtin_amdgcn_mfma_f32_16x16x32_bf16(ap, bv, accO[nd],
                                                           0, 0, 0);
      }
    }
  }

  float inv[4];
#pragma unroll
  for (int r = 0; r < 4; ++r) inv[r] = 1.0f / lsum[r];
#pragma unroll
  for (int nd = 0; nd < 4; ++nd)
#pragma unroll
    for (int r = 0; r < 4; ++r)
      ctx[(qrow0 + w * 16 + quad * 4 + r) * 1024 + hc + nd * 16 + cl] =
          f2b(accO[nd][r] * inv[r]);
}

// ---------------------------------------------------------------------------
// Conversions & summary-branch helpers
// ---------------------------------------------------------------------------
__global__ void cvt_x(const float* __restrict__ x, u16* __restrict__ xb) {
  const size_t i = ((size_t)blockIdx.x * 256 + threadIdx.x) * 4;
  float4 v = *(const float4*)&x[i];
  u16x4 o;
  o[0] = f2b(v.x); o[1] = f2b(v.y); o[2] = f2b(v.z); o[3] = f2b(v.w);
  *(u16x4*)&xb[i] = o;
}

// mean over each 256-token block; reads bf16 Xb (half the traffic of f32 x)
__global__ void block_mean(const u16* __restrict__ xb, u16* __restrict__ xm) {
  const int g = blockIdx.x >> 2;
  const int d = ((blockIdx.x & 3) << 8) + threadIdx.x;
  const u16* p = xb + (size_t)g * 256 * 1024 + d;
  float s = 0.f;
  for (int t = 0; t < 256; ++t) s += b2f(p[(size_t)t * 1024]);
  xm[(size_t)g * 1024 + d] = f2b(s * (1.0f / 256.0f));
}

__global__ void summ_attn(const u16* __restrict__ SQ, const u16* __restrict__ SK,
                          const u16* __restrict__ SV, u16* __restrict__ sctx) {
  const int b = blockIdx.x >> 4;
  const int h = blockIdx.x & 15;
  const int t = threadIdx.x;
  __shared__ float Qf[16][64];
  __shared__ float Kf[16][64];
  __shared__ float Vf[16][64];
  __shared__ float sc[16][16];
  for (int i = t; i < 1024; i += 64) {
    const int r = i >> 6, d = i & 63;
    const size_t off = (size_t)(b * 16 + r) * 1024 + h * 64 + d;
    Qf[r][d] = b2f(SQ[off]);
    Kf[r][d] = b2f(SK[off]);
    Vf[r][d] = b2f(SV[off]);
  }
  __syncthreads();
  {
    const int i = t >> 2, j0 = t & 3;
#pragma unroll
    for (int jj = 0; jj < 4; ++jj) {
      const int j = j0 + jj * 4;
      float s = 0.f;
      for (int d = 0; d < 64; ++d) s += Qf[i][d] * Kf[j][d];
      sc[i][j] = s * 0.125f;
    }
  }
  __syncthreads();
  if (t < 16) {
    float m = -1e30f;
    for (int j = 0; j < 16; ++j) m = fmaxf(m, sc[t][j]);
    float l = 0.f;
    for (int j = 0; j < 16; ++j) {
      float p = exp2f((sc[t][j] - m) * 1.44269504f);
      sc[t][j] = p;
      l += p;
    }
    const float inv = 1.0f / l;
    for (int j = 0; j < 16; ++j) sc[t][j] *= inv;
  }
  __syncthreads();
  {
    const int i = t >> 2, d0 = (t & 3) * 16;
    for (int dd = 0; dd < 16; ++dd) {
      float a = 0.f;
      for (int j = 0; j < 16; ++j) a += sc[i][j] * Vf[j][d0 + dd];
      sctx[(size_t)(b * 16 + i) * 1024 + h * 64 + d0 + dd] = f2b(a);
    }
  }
}

struct TPtrs { const float* src[9]; u16* dst[9]; };

__global__ void cvt_transpose9(TPtrs p) {
  const float* src = p.src[blockIdx.z];
  u16* dst         = p.dst[blockIdx.z];
  __shared__ u16 tile[64][72];
  const int r0 = blockIdx.x * 64, c0 = blockIdx.y * 64;
  for (int i = threadIdx.x; i < 1024; i += 256) {
    const int row = i >> 4, c4 = (i & 15) * 4;
    float4 v = *(const float4*)&src[(size_t)(r0 + row) * 1024 + c0 + c4];
    tile[row][c4 + 0] = f2b(v.x);
    tile[row][c4 + 1] = f2b(v.y);
    tile[row][c4 + 2] = f2b(v.z);
    tile[row][c4 + 3] = f2b(v.w);
  }
  __syncthreads();
  for (int i = threadIdx.x; i < 512; i += 256) {
    const int row = i >> 3, c8 = (i & 7) * 8;
    u16x8 v;
#pragma unroll
    for (int j = 0; j < 8; ++j) v[j] = tile[c8 + j][row];
    *(u16x8*)&dst[(size_t)(c0 + row) * 1024 + r0 + c8] = v;
  }
}

// ---------------------------------------------------------------------------
extern "C" void kernel_launch(void* const* d_in, const int* in_sizes, int n_in,
                              void* d_out, int out_size, void* d_ws, size_t ws_size,
                              hipStream_t stream) {
  const float* x    = (const float*)d_in[0];
  const float* lqw  = (const float*)d_in[1];
  const float* lqb  = (const float*)d_in[2];
  const float* lkw  = (const float*)d_in[3];
  const float* lkb  = (const float*)d_in[4];
  const float* lvw  = (const float*)d_in[5];
  const float* lvb  = (const float*)d_in[6];
  const float* low_ = (const float*)d_in[7];
  const float* lob  = (const float*)d_in[8];
  const float* pb   = (const float*)d_in[9];
  const float* sqw  = (const float*)d_in[10];
  const float* sqb  = (const float*)d_in[11];
  const float* skw  = (const float*)d_in[12];
  const float* skb  = (const float*)d_in[13];
  const float* svw  = (const float*)d_in[14];
  const float* svb  = (const float*)d_in[15];
  const float* sow  = (const float*)d_in[16];
  const float* sob  = (const float*)d_in[17];
  const float* smw  = (const float*)d_in[18];
  const float* smb  = (const float*)d_in[19];

  static int s_attr_done = 0;
  if (!s_attr_done) {
    (void)hipFuncSetAttribute((const void*)gemm_bt256,
                              hipFuncAttributeMaxDynamicSharedMemorySize,
                              131072);
    s_attr_done = 1;
  }

  char* W = (char*)d_ws;
  size_t off = 0;
  u16* wt[9];
  for (int i = 0; i < 9; ++i) { wt[i] = (u16*)(W + off); off += (size_t)1024 * 1024 * 2; }
  u16* Xb  = (u16*)(W + off); off += (size_t)16384 * 1024 * 2;
  u16* XM  = (u16*)(W + off); off += (size_t)128 * 1024 * 2;
  u16* SMR = (u16*)(W + off); off += (size_t)128 * 1024 * 2;
  u16* SQp = (u16*)(W + off); off += (size_t)128 * 1024 * 2;
  u16* SKp = (u16*)(W + off); off += (size_t)128 * 1024 * 2;
  u16* SVp = (u16*)(W + off); off += (size_t)128 * 1024 * 2;
  u16* SCT = (u16*)(W + off); off += (size_t)128 * 1024 * 2;
  float* SMM = (float*)(W + off); off += (size_t)128 * 1024 * 4;
  const size_t fixedB = off;

  int CH = 256;
  for (int c = 16384; c >= 256; c >>= 1) {
    if (fixedB + (size_t)4 * c * 1024 * 2 <= ws_size) { CH = c; break; }
  }
  u16* Qb  = (u16*)(W + fixedB);
  u16* Kb  = Qb + (size_t)CH * 1024;
  u16* Vb  = Kb + (size_t)CH * 1024;
  u16* CTX = Vb + (size_t)CH * 1024;

  TPtrs tp;
  tp.src[0] = lqw; tp.src[1] = lkw; tp.src[2] = lvw; tp.src[3] = low_;
  tp.src[4] = sqw; tp.src[5] = skw; tp.src[6] = svw; tp.src[7] = sow;
  tp.src[8] = smw;
  for (int i = 0; i < 9; ++i) tp.dst[i] = wt[i];
  cvt_transpose9<<<dim3(16, 16, 9), 256, 0, stream>>>(tp);

  cvt_x<<<dim3(16384), 256, 0, stream>>>(x, Xb);
  block_mean<<<dim3(256), 256, 0, stream>>>(Xb, XM);

  GemmArgs g1{};
  g1.A = XM; g1.BT0 = g1.BT1 = g1.BT2 = wt[8];
  g1.b0 = g1.b1 = g1.b2 = smb; g1.summ = nullptr; g1.srow0 = 0;
  g1.C0 = g1.C1 = g1.C2 = SMR; g1.Cf = nullptr;
  gemm_bt<<<dim3(1, 8, 1), 256, 0, stream>>>(g1);

  GemmArgs g2{};
  g2.A = SMR; g2.BT0 = wt[4]; g2.BT1 = wt[5]; g2.BT2 = wt[6];
  g2.b0 = sqb; g2.b1 = skb; g2.b2 = svb; g2.summ = nullptr; g2.srow0 = 0;
  g2.C0 = SQp; g2.C1 = SKp; g2.C2 = SVp; g2.Cf = nullptr;
  gemm_bt<<<dim3(1, 8, 3), 256, 0, stream>>>(g2);

  summ_attn<<<dim3(64), 64, 0, stream>>>(SQp, SKp, SVp, SCT);

  GemmArgs g3{};
  g3.A = SCT; g3.BT0 = g3.BT1 = g3.BT2 = wt[7];
  g3.b0 = g3.b1 = g3.b2 = sob; g3.summ = nullptr; g3.srow0 = 0;
  g3.C0 = g3.C1 = g3.C2 = nullptr; g3.Cf = SMM;
  gemm_bt<<<dim3(1, 8, 1), 256, 0, stream>>>(g3);

  for (int base = 0; base < 16384; base += CH) {
    GemmArgs g4{};
    g4.A = Xb + (size_t)base * 1024;
    g4.BT0 = wt[0]; g4.BT1 = wt[1]; g4.BT2 = wt[2];
    g4.b0 = lqb; g4.b1 = lkb; g4.b2 = lvb; g4.summ = nullptr; g4.srow0 = 0;
    g4.C0 = Qb; g4.C1 = Kb; g4.C2 = Vb; g4.Cf = nullptr;
    gemm_bt256<<<dim3(CH / 256, 4, 3), 512, 131072, stream>>>(g4);

    local_attn<<<dim3(4, 16, CH / 256), 256, 0, stream>>>(Qb, Kb, Vb, pb, CTX);

    GemmArgs g5{};
    g5.A = CTX; g5.BT0 = g5.BT1 = g5.BT2 = wt[3];
    g5.b0 = g5.b1 = g5.b2 = lob; g5.summ = SMM; g5.srow0 = base >> 8;
    g5.C0 = g5.C1 = g5.C2 = nullptr;
    g5.Cf = (float*)d_out + (size_t)base * 1024;
    gemm_bt256<<<dim3(CH / 256, 4, 1), 512, 131072, stream>>>(g5);
  }

  (void)in_sizes; (void)n_in; (void)out_size;
}